// Round 5
// baseline (1756.046 us; speedup 1.0000x reference)
//
#include <hip/hip_runtime.h>
#include <hip/hip_bf16.h>
#include <stdint.h>

// ---------------------------------------------------------------------------
// LinearFLHGS: per-group(64) symmetric int4 quant-dequant of x and w, then
// C = x_dq @ w_dq^T.  Round 5: tile-level register pipelining.
// 256x256, 8 waves, BK=64, double-buffered LDS.  Tile t's MFMAs consume
// frags_cur (registers, no LDS dependency) while tile t+1's 24 fragments are
// read into frags_next (groups of 8 pinned between quadrants by
// sched_barrier(0)) -> ds_read and MFMA overlap BY DATAFLOW.  Stage t+2 into
// the dead buffer at tile start; one barrier + lgkmcnt(0) + vmcnt(0) per tile.
// Swizzle (0 conflicts), epilogue, quant proven in rounds 1-4.
// ---------------------------------------------------------------------------

typedef __bf16 bf16x8 __attribute__((ext_vector_type(8)));
typedef float f32x4 __attribute__((ext_vector_type(4)));

static __device__ __forceinline__ uint16_t f32_to_bf16_rne(float f) {
    uint32_t u = __float_as_uint(f);
    uint32_t r = (u + 0x7fffu + ((u >> 16) & 1u)) >> 16;
    return (uint16_t)r;
}

__global__ void quant_kernel(const float* __restrict__ in,
                             uint16_t* __restrict__ out, int total4) {
    int nthreads = gridDim.x * blockDim.x;
    int t = blockIdx.x * blockDim.x + threadIdx.x;
    for (int i = t; i < total4; i += nthreads) {
        float4 v = ((const float4*)in)[i];
        float amax = fmaxf(fmaxf(fabsf(v.x), fabsf(v.y)),
                           fmaxf(fabsf(v.z), fabsf(v.w)));
        #pragma unroll
        for (int m = 1; m <= 8; m <<= 1)
            amax = fmaxf(amax, __shfl_xor(amax, m, 64));
        float s = fmaxf(amax / 7.0f, 1e-8f);
        float q0 = fminf(fmaxf(rintf(v.x / s), -8.0f), 7.0f);
        float q1 = fminf(fmaxf(rintf(v.y / s), -8.0f), 7.0f);
        float q2 = fminf(fmaxf(rintf(v.z / s), -8.0f), 7.0f);
        float q3 = fminf(fmaxf(rintf(v.w / s), -8.0f), 7.0f);
        ushort4 o;
        o.x = f32_to_bf16_rne(q0 * s);
        o.y = f32_to_bf16_rne(q1 * s);
        o.z = f32_to_bf16_rne(q2 * s);
        o.w = f32_to_bf16_rne(q3 * s);
        ((ushort4*)out)[i] = o;
    }
}

#define BM 256
#define BN 256
#define BK 64

#define FENCE() asm volatile("" ::: "memory")
#define SB0()   __builtin_amdgcn_sched_barrier(0)

__global__ __launch_bounds__(512, 2) void gemm_kernel(
        const uint16_t* __restrict__ A, const uint16_t* __restrict__ B,
        float* __restrict__ C, int M, int N, int K) {
    __shared__ uint16_t As[2][2][128 * 64];
    __shared__ uint16_t Bs[2][2][128 * 64];

    const int NTt = K >> 6;   // 64 K-tiles (even)

    int nwg = gridDim.x;
    int bid = blockIdx.x;
    int swz = bid;
    if ((nwg & 7) == 0) {
        int cpx = nwg >> 3;
        swz = (bid & 7) * cpx + (bid >> 3);
    }
    int nbn = N / BN;
    int bm = swz / nbn, bn = swz % nbn;

    int tid = threadIdx.x;
    int lane = tid & 63;
    int wid = tid >> 6;
    int wm = wid >> 2;        // 0..1 : 128-row band of A
    int wn = wid & 3;         // 0..3 : 64-col band of B

    const int rowA0 = bm * BM;
    const int colB0 = bn * BN;

    int srow = lane >> 3;
    int scol = ((lane & 7) ^ (lane >> 3)) << 3;

    int rl = lane & 15;
    int cg = lane >> 4;
    int coff[2];
    coff[0] = ((0 + cg) ^ (rl & 7)) << 3;
    coff[1] = ((4 + cg) ^ (rl & 7)) << 3;

    const int bhalf = wn >> 1;
    const int brow0 = (wn & 1) * 64;

    f32x4 acc[8][4] = {};
    bf16x8 fa0[8][2], fb0[4][2], fa1[8][2], fb1[4][2];

    auto stageA = [&](int buf, int half, int t) {
        #pragma unroll
        for (int j = 0; j < 2; ++j) {
            int rowin = wid * 16 + j * 8;
            const uint16_t* g = A + (size_t)(rowA0 + half * 128 + rowin + srow) * K
                                  + t * 64 + scol;
            uint16_t* l = &As[buf][half][rowin * 64];
            __builtin_amdgcn_global_load_lds(
                (const __attribute__((address_space(1))) void*)g,
                (__attribute__((address_space(3))) void*)l, 16, 0, 0);
        }
    };
    auto stageB = [&](int buf, int half, int t) {
        #pragma unroll
        for (int j = 0; j < 2; ++j) {
            int rowin = wid * 16 + j * 8;
            const uint16_t* g = B + (size_t)(colB0 + half * 128 + rowin + srow) * K
                                  + t * 64 + scol;
            uint16_t* l = &Bs[buf][half][rowin * 64];
            __builtin_amdgcn_global_load_lds(
                (const __attribute__((address_space(1))) void*)g,
                (__attribute__((address_space(3))) void*)l, 16, 0, 0);
        }
    };

    // read 4 A-fragments (rows lo*16 .. lo*16+63 of this wave's band)
    auto readA4 = [&](bf16x8 (&dst)[8][2], int lo, int buf) {
        #pragma unroll
        for (int mi = 0; mi < 4; ++mi)
            #pragma unroll
            for (int ks = 0; ks < 2; ++ks)
                dst[lo + mi][ks] =
                    *(const bf16x8*)&As[buf][wm][((lo + mi) * 16 + rl) * 64 + coff[ks]];
    };
    // read all 4 B-fragments of this wave's 64-col band
    auto readB4 = [&](bf16x8 (&dst)[4][2], int buf) {
        #pragma unroll
        for (int ni = 0; ni < 4; ++ni)
            #pragma unroll
            for (int ks = 0; ks < 2; ++ks)
                dst[ni][ks] =
                    *(const bf16x8*)&Bs[buf][bhalf][(brow0 + ni * 16 + rl) * 64 + coff[ks]];
    };

    auto quad = [&](const bf16x8 (&af)[8][2], int alo,
                    const bf16x8 (&bf)[4][2], int blo, int mo, int no) {
        __builtin_amdgcn_s_setprio(1);
        #pragma unroll
        for (int mi = 0; mi < 4; ++mi)
            #pragma unroll
            for (int ni = 0; ni < 2; ++ni)
                #pragma unroll
                for (int ks = 0; ks < 2; ++ks)
                    acc[mo + mi][no + ni] = __builtin_amdgcn_mfma_f32_16x16x32_bf16(
                        af[alo + mi][ks], bf[blo + ni][ks], acc[mo + mi][no + ni], 0, 0, 0);
        __builtin_amdgcn_s_setprio(0);
    };

    // ---- prologue: stage tiles 0,1; land both; read tile-0 frags; seal ----
    stageA(0, 0, 0); stageA(0, 1, 0); stageB(0, 0, 0); stageB(0, 1, 0);
    stageA(1, 0, 1); stageA(1, 1, 1); stageB(1, 0, 1); stageB(1, 1, 1);
    asm volatile("s_waitcnt vmcnt(0)" ::: "memory");
    FENCE(); __builtin_amdgcn_s_barrier(); FENCE();
    readA4(fa0, 0, 0); readA4(fa0, 4, 0); readB4(fb0, 0);
    asm volatile("s_waitcnt lgkmcnt(0)" ::: "memory");
    SB0();
    FENCE(); __builtin_amdgcn_s_barrier(); FENCE();

    // ---- main loop: 2 tiles per iteration, frag sets ping-pong ----
#define TILE(FA_CUR, FB_CUR, FA_NXT, FB_NXT, CB, T)                          \
    {                                                                        \
        const int nb_ = (CB) ^ 1;                                            \
        if ((T) + 2 < NTt) { stageA((CB), 0, (T) + 2); stageA((CB), 1, (T) + 2); } \
        readA4(FA_NXT, 0, nb_);                                              \
        SB0();                                                               \
        quad(FA_CUR, 0, FB_CUR, 0, 0, 0);                                    \
        SB0();                                                               \
        if ((T) + 2 < NTt) { stageB((CB), 0, (T) + 2); stageB((CB), 1, (T) + 2); } \
        readB4(FB_NXT, nb_);                                                 \
        SB0();                                                               \
        quad(FA_CUR, 0, FB_CUR, 2, 0, 2);                                    \
        SB0();                                                               \
        readA4(FA_NXT, 4, nb_);                                              \
        SB0();                                                               \
        quad(FA_CUR, 4, FB_CUR, 0, 4, 0);                                    \
        SB0();                                                               \
        quad(FA_CUR, 4, FB_CUR, 2, 4, 2);                                    \
        asm volatile("s_waitcnt lgkmcnt(0)" ::: "memory");                   \
        asm volatile("s_waitcnt vmcnt(0)" ::: "memory");                     \
        SB0();                                                               \
        FENCE(); __builtin_amdgcn_s_barrier(); FENCE();                      \
    }

    for (int it = 0; it < (NTt >> 1); ++it) {
        TILE(fa0, fb0, fa1, fb1, 0, 2 * it);
        TILE(fa1, fb1, fa0, fb0, 1, 2 * it + 1);
    }
#undef TILE

    // ---- epilogue: D map col = lane&15, row = (lane>>4)*4 + reg ----
    int cl = lane & 15;
    int rq = (lane >> 4) * 4;
    #pragma unroll
    for (int mi = 0; mi < 8; ++mi) {
        #pragma unroll
        for (int ni = 0; ni < 4; ++ni) {
            int row = rowA0 + wm * 128 + mi * 16 + rq;
            int col = colB0 + wn * 64 + ni * 16 + cl;
            float* cp = C + (size_t)row * N + col;
            #pragma unroll
            for (int r = 0; r < 4; ++r)
                cp[(size_t)r * N] = acc[mi][ni][r];
        }
    }
}

extern "C" void kernel_launch(void* const* d_in, const int* in_sizes, int n_in,
                              void* d_out, int out_size, void* d_ws, size_t ws_size,
                              hipStream_t stream) {
    const float* x = (const float*)d_in[0];
    const float* w = (const float*)d_in[1];
    float* out = (float*)d_out;

    const int K = 4096;
    const int T = in_sizes[0] / K;   // 8192
    const int O = in_sizes[1] / K;   // 4096

    uint16_t* xq = (uint16_t*)d_ws;
    uint16_t* wq = (uint16_t*)((char*)d_ws + (size_t)T * K * 2);

    quant_kernel<<<2048, 256, 0, stream>>>(x, xq, (T * K) >> 2);
    quant_kernel<<<2048, 256, 0, stream>>>(w, wq, (O * K) >> 2);

    int nwg = (T / BM) * (O / BN);   // 512
    gemm_kernel<<<nwg, 512, 0, stream>>>(xq, wq, out, T, O, K);
}

// Round 6
// 328.144 us; speedup vs baseline: 5.3514x; 5.3514x over previous
//
#include <hip/hip_runtime.h>
#include <hip/hip_bf16.h>
#include <stdint.h>

// ---------------------------------------------------------------------------
// LinearFLHGS: per-group(64) symmetric int4 quant-dequant of x and w, then
// C = x_dq @ w_dq^T.  Round 6: dataflow pipelining WITHOUT extra registers.
// 256x256, 8 waves, BK=64, double-buffered LDS.  Single 96-VGPR fragment set
// (A0=aLo, A1=aHi, B0=bLo, B1=bHi); quadrant order LoLo, HiLo, LoHi, HiHi
// makes each block dead exactly one quadrant before its refill read:
//   Q1: MFMA(A0,B0) + read A1,B1 <- tile t   (ct)
//   [lgkm0 + barrier#1]  stage(t+2 -> ct)
//   Q2: MFMA(A1,B0)
//   [vmcnt(8) + barrier#2]   (stage t+1 landed, cross-wave)
//   Q3: MFMA(A0,B1) + read B0 <- bLo(t+1)  (nt)
//   Q4: MFMA(A1,B1) + read A0 <- aLo(t+1)  (nt)
// ds_read drains under MFMA by dataflow; registers recycled every tile.
// ---------------------------------------------------------------------------

typedef __bf16 bf16x8 __attribute__((ext_vector_type(8)));
typedef float f32x4 __attribute__((ext_vector_type(4)));

static __device__ __forceinline__ uint16_t f32_to_bf16_rne(float f) {
    uint32_t u = __float_as_uint(f);
    uint32_t r = (u + 0x7fffu + ((u >> 16) & 1u)) >> 16;
    return (uint16_t)r;
}

__global__ void quant_kernel(const float* __restrict__ in,
                             uint16_t* __restrict__ out, int total4) {
    int nthreads = gridDim.x * blockDim.x;
    int t = blockIdx.x * blockDim.x + threadIdx.x;
    for (int i = t; i < total4; i += nthreads) {
        float4 v = ((const float4*)in)[i];
        float amax = fmaxf(fmaxf(fabsf(v.x), fabsf(v.y)),
                           fmaxf(fabsf(v.z), fabsf(v.w)));
        #pragma unroll
        for (int m = 1; m <= 8; m <<= 1)
            amax = fmaxf(amax, __shfl_xor(amax, m, 64));
        float s = fmaxf(amax / 7.0f, 1e-8f);
        float q0 = fminf(fmaxf(rintf(v.x / s), -8.0f), 7.0f);
        float q1 = fminf(fmaxf(rintf(v.y / s), -8.0f), 7.0f);
        float q2 = fminf(fmaxf(rintf(v.z / s), -8.0f), 7.0f);
        float q3 = fminf(fmaxf(rintf(v.w / s), -8.0f), 7.0f);
        ushort4 o;
        o.x = f32_to_bf16_rne(q0 * s);
        o.y = f32_to_bf16_rne(q1 * s);
        o.z = f32_to_bf16_rne(q2 * s);
        o.w = f32_to_bf16_rne(q3 * s);
        ((ushort4*)out)[i] = o;
    }
}

#define BM 256
#define BN 256
#define BK 64

#define FENCE() asm volatile("" ::: "memory")
#define SB0()   __builtin_amdgcn_sched_barrier(0)

__global__ __launch_bounds__(512, 2) void gemm_kernel(
        const uint16_t* __restrict__ A, const uint16_t* __restrict__ B,
        float* __restrict__ C, int M, int N, int K) {
    __shared__ uint16_t As[2][2][128 * 64];
    __shared__ uint16_t Bs[2][2][128 * 64];

    const int NTt = K >> 6;

    int nwg = gridDim.x;
    int bid = blockIdx.x;
    int swz = bid;
    if ((nwg & 7) == 0) {
        int cpx = nwg >> 3;
        swz = (bid & 7) * cpx + (bid >> 3);
    }
    int nbn = N / BN;
    int bm = swz / nbn, bn = swz % nbn;

    int tid = threadIdx.x;
    int lane = tid & 63;
    int wid = tid >> 6;
    int wm = wid >> 2;        // 0..1 : 128-row band of A
    int wn = wid & 3;         // 0..3 : 64-col band of B

    const int rowA0 = bm * BM;
    const int colB0 = bn * BN;

    int srow = lane >> 3;
    int scol = ((lane & 7) ^ (lane >> 3)) << 3;

    int rl = lane & 15;
    int cg = lane >> 4;
    int coff[2];
    coff[0] = ((0 + cg) ^ (rl & 7)) << 3;
    coff[1] = ((4 + cg) ^ (rl & 7)) << 3;

    const int bhalf = wn >> 1;
    const int brow0 = (wn & 1) * 64;

    f32x4 acc[8][4] = {};
    // single fragment set: 96 VGPRs total
    bf16x8 A0[4][2], A1[4][2], B0[2][2], B1[2][2];

    auto stageA = [&](int buf, int half, int t) {
        #pragma unroll
        for (int j = 0; j < 2; ++j) {
            int rowin = wid * 16 + j * 8;
            const uint16_t* g = A + (size_t)(rowA0 + half * 128 + rowin + srow) * K
                                  + t * 64 + scol;
            uint16_t* l = &As[buf][half][rowin * 64];
            __builtin_amdgcn_global_load_lds(
                (const __attribute__((address_space(1))) void*)g,
                (__attribute__((address_space(3))) void*)l, 16, 0, 0);
        }
    };
    auto stageB = [&](int buf, int half, int t) {
        #pragma unroll
        for (int j = 0; j < 2; ++j) {
            int rowin = wid * 16 + j * 8;
            const uint16_t* g = B + (size_t)(colB0 + half * 128 + rowin + srow) * K
                                  + t * 64 + scol;
            uint16_t* l = &Bs[buf][half][rowin * 64];
            __builtin_amdgcn_global_load_lds(
                (const __attribute__((address_space(1))) void*)g,
                (__attribute__((address_space(3))) void*)l, 16, 0, 0);
        }
    };

    // read 4 A-fragments (rows lo .. lo+63 of this wave's 128-row band)
    auto readA4 = [&](bf16x8 (&dst)[4][2], int lo, int buf) {
        #pragma unroll
        for (int mi = 0; mi < 4; ++mi)
            #pragma unroll
            for (int ks = 0; ks < 2; ++ks)
                dst[mi][ks] =
                    *(const bf16x8*)&As[buf][wm][((lo + mi) * 16 + rl) * 64 + coff[ks]];
    };
    // read 2 B-fragments (cols lo .. lo+31 of this wave's 64-col band)
    auto readB2 = [&](bf16x8 (&dst)[2][2], int lo, int buf) {
        #pragma unroll
        for (int ni = 0; ni < 2; ++ni)
            #pragma unroll
            for (int ks = 0; ks < 2; ++ks)
                dst[ni][ks] =
                    *(const bf16x8*)&Bs[buf][bhalf][(brow0 + (lo + ni) * 16 + rl) * 64 + coff[ks]];
    };

    auto quad = [&](const bf16x8 (&af)[4][2], const bf16x8 (&bf)[2][2],
                    int mo, int no) {
        __builtin_amdgcn_s_setprio(1);
        #pragma unroll
        for (int mi = 0; mi < 4; ++mi)
            #pragma unroll
            for (int ni = 0; ni < 2; ++ni)
                #pragma unroll
                for (int ks = 0; ks < 2; ++ks)
                    acc[mo + mi][no + ni] = __builtin_amdgcn_mfma_f32_16x16x32_bf16(
                        af[mi][ks], bf[ni][ks], acc[mo + mi][no + ni], 0, 0, 0);
        __builtin_amdgcn_s_setprio(0);
    };

    // ---- prologue: stage tiles 0,1; land tile 0; preload A0,B0 of tile 0 ----
    stageA(0, 0, 0); stageA(0, 1, 0); stageB(0, 0, 0); stageB(0, 1, 0);
    stageA(1, 0, 1); stageA(1, 1, 1); stageB(1, 0, 1); stageB(1, 1, 1);
    asm volatile("s_waitcnt vmcnt(8)" ::: "memory");   // tile 0 landed
    FENCE(); __builtin_amdgcn_s_barrier(); FENCE();
    readA4(A0, 0, 0);        // aLo(0)
    readB2(B0, 0, 0);        // bLo(0)

    for (int t = 0; t < NTt; ++t) {
        int ct = t & 1, nt = ct ^ 1;

        // ---- Q1: read A1<-aHi(t), B1<-bHi(t) from ct; MFMA(A0,B0) ----
        readA4(A1, 4, ct);
        readB2(B1, 2, ct);
        SB0();
        quad(A0, B0, 0, 0);
        SB0();

        // ---- seal all reads of ct; stage t+2 into ct ----
        asm volatile("s_waitcnt lgkmcnt(0)" ::: "memory");
        SB0();
        FENCE(); __builtin_amdgcn_s_barrier(); FENCE();   // barrier #1
        if (t + 2 < NTt) {
            stageA(ct, 0, t + 2); stageA(ct, 1, t + 2);
            stageB(ct, 0, t + 2); stageB(ct, 1, t + 2);
        }
        SB0();

        // ---- Q2: MFMA(A1,B0) ----
        quad(A1, B0, 4, 0);
        SB0();

        // ---- stage(t+1) landed (cross-wave) -> nt readable ----
        if (t + 2 < NTt) asm volatile("s_waitcnt vmcnt(8)" ::: "memory");
        else             asm volatile("s_waitcnt vmcnt(0)" ::: "memory");
        FENCE(); __builtin_amdgcn_s_barrier(); FENCE();   // barrier #2

        // ---- Q3: read B0<-bLo(t+1) from nt; MFMA(A0,B1) ----
        if (t + 1 < NTt) readB2(B0, 0, nt);
        SB0();
        quad(A0, B1, 0, 2);
        SB0();

        // ---- Q4: read A0<-aLo(t+1) from nt; MFMA(A1,B1) ----
        if (t + 1 < NTt) readA4(A0, 0, nt);
        SB0();
        quad(A1, B1, 4, 2);
        SB0();
        // no tile-end barrier: next tile's barrier#1 seals nt reads before
        // any stage into nt; A0/B0 deps are per-wave (compiler counted lgkm).
    }

    // ---- epilogue: D map col = lane&15, row = (lane>>4)*4 + reg ----
    int cl = lane & 15;
    int rq = (lane >> 4) * 4;
    #pragma unroll
    for (int mi = 0; mi < 8; ++mi) {
        #pragma unroll
        for (int ni = 0; ni < 4; ++ni) {
            int row = rowA0 + wm * 128 + mi * 16 + rq;
            int col = colB0 + wn * 64 + ni * 16 + cl;
            float* cp = C + (size_t)row * N + col;
            #pragma unroll
            for (int r = 0; r < 4; ++r)
                cp[(size_t)r * N] = acc[mi][ni][r];
        }
    }
}

extern "C" void kernel_launch(void* const* d_in, const int* in_sizes, int n_in,
                              void* d_out, int out_size, void* d_ws, size_t ws_size,
                              hipStream_t stream) {
    const float* x = (const float*)d_in[0];
    const float* w = (const float*)d_in[1];
    float* out = (float*)d_out;

    const int K = 4096;
    const int T = in_sizes[0] / K;   // 8192
    const int O = in_sizes[1] / K;   // 4096

    uint16_t* xq = (uint16_t*)d_ws;
    uint16_t* wq = (uint16_t*)((char*)d_ws + (size_t)T * K * 2);

    quant_kernel<<<2048, 256, 0, stream>>>(x, xq, (T * K) >> 2);
    quant_kernel<<<2048, 256, 0, stream>>>(w, wq, (O * K) >> 2);

    int nwg = (T / BM) * (O / BN);   // 512
    gemm_kernel<<<nwg, 512, 0, stream>>>(xq, wq, out, T, O, K);
}